// Round 8
// baseline (447.632 us; speedup 1.0000x reference)
//
#include <hip/hip_runtime.h>

#define Bn 32
#define Tn 24
#define Dn 32
#define Hn 32
#define Cn 1024
#define DC (Dn*Cn)      /* 32768 */
#define TDC (Tn*Dn*Cn)  /* 786432 */
#define MP 34
#define PPXN (MP*MP)    /* 1156 */
#define IMGS (MP*MP*32) /* shorts per image (4 planes * 1156 * 8) */
#define SCALE 1.442695041f

typedef __attribute__((ext_vector_type(8))) short bf16x8;
typedef __attribute__((ext_vector_type(4))) float f32x4;

union U8 { unsigned u[4]; int4 i; bf16x8 v; };

__device__ __forceinline__ unsigned cvt_pk(float lo, float hi) {
    unsigned r; asm("v_cvt_pk_bf16_f32 %0, %1, %2" : "=v"(r) : "v"(lo), "v"(hi)); return r;
}
__device__ __forceinline__ float lo16f(unsigned u) { return __builtin_bit_cast(float, u << 16); }
__device__ __forceinline__ float hi16f(unsigned u) { return __builtin_bit_cast(float, u & 0xffff0000u); }
__device__ __forceinline__ float rcp_(float x) { return __builtin_amdgcn_rcpf(x); }
__device__ __forceinline__ float exp2_(float x) { return __builtin_amdgcn_exp2f(x); }

struct __align__(16) LdsL {
    float X[2][16][16][36];  // [buf][c][b][d pad36] fp32
    float H[2][16][16][36];  // [buf][c][b][h pad36] fp32
};

// ---- zero the 1-px halo ring of every (img, chunk) plane ----
__global__ __launch_bounds__(512)
void zero_halo(unsigned short* __restrict__ sp) {
    int gid = blockIdx.x * 512 + threadIdx.x;
    if (gid >= 3072 * 132) return;
    int plane = gid / 132;
    int r = gid - plane * 132;
    int m, n;
    if (r < 34)       { m = 0;      n = r; }
    else if (r < 68)  { m = 33;     n = r - 34; }
    else if (r < 100) { m = r - 67; n = 0; }
    else              { m = r - 99; n = 33; }
    int4 z = {0, 0, 0, 0};
    *(int4*)(sp + ((size_t)plane * PPXN + m * MP + n) * 8) = z;
}

// ---- LSTM: grid 128 = 64 cellgroups x 2 bslices; 1024 thr = 16 waves ----
// wave = cell ci (16 consecutive cells); M=16 (bslice), N=128 gates (8 q-tiles).
__global__ __launch_bounds__(1024, 1)
void lstm_k8(const float* __restrict__ x,
             const float* __restrict__ Wih,
             const float* __restrict__ Whh,
             const float* __restrict__ bih,
             const float* __restrict__ bhh,
             unsigned short* __restrict__ sp)
{
    __shared__ LdsL lds;
    const int tid  = threadIdx.x;
    const int lane = tid & 63;
    const int wave = tid >> 6;          // = cell index ci, also staging batch row
    const int l16  = lane & 15;
    const int kg   = lane >> 4;
    const int bid  = blockIdx.x;
    const int xcd  = bid & 7, r2 = bid >> 3;
    const int cg   = xcd * 8 + (r2 & 7);     // 0..63, XCD-contiguous
    const int bs   = r2 >> 3;                // 0..1
    const int cellbase = cg * 16;
    const int cell = cellbase + wave;
    const int gb0  = bs * 16;

    // ---- W fragments: 8 q-tiles of 16 gate-cols, split hi/lo, pre-scaled ----
    U8 wihh[8], wihl[8], whhh[8], whhl[8];
    float biasr[8];
#pragma unroll
    for (int q = 0; q < 8; ++q) {
        const int g = q * 16 + l16;
        const float* wp = Wih + (size_t)cell * 4096 + g * 32 + kg * 8;
        const float* hp = Whh + (size_t)cell * 4096 + g * 32 + kg * 8;
        float wv[8], hv[8];
#pragma unroll
        for (int j = 0; j < 8; ++j) { wv[j] = wp[j] * SCALE; hv[j] = hp[j] * SCALE; }
#pragma unroll
        for (int p = 0; p < 4; ++p) {
            unsigned a = cvt_pk(wv[2*p], wv[2*p+1]);
            wihh[q].u[p] = a;
            wihl[q].u[p] = cvt_pk(wv[2*p] - lo16f(a), wv[2*p+1] - hi16f(a));
            unsigned b = cvt_pk(hv[2*p], hv[2*p+1]);
            whhh[q].u[p] = b;
            whhl[q].u[p] = cvt_pk(hv[2*p] - lo16f(b), hv[2*p+1] - hi16f(b));
        }
        biasr[q] = (bih[cell * 128 + g] + bhh[cell * 128 + g]) * SCALE;
    }

    // ---- x staging: thread -> (b = wave, d = lane>>1, chalf = lane&1) ----
    const int sd = lane >> 1, sch = lane & 1;
    const float* xb = x + (size_t)(gb0 + wave) * TDC + (size_t)sd * Cn + cellbase + sch * 8;
    float4 gA = *(const float4*)xb;
    float4 gB = *(const float4*)(xb + 4);

    // ---- sp store constants (waves 0..3 store; lane -> cell_l = lane&15) ----
    const int mrow = cg >> 1, n0 = (cg & 1) * 16;
    const int ppx0 = (mrow + 1) * MP + n0 + 1;
    const int cell_l = lane & 15, bsub = lane >> 4;

    float hD[8] = {}, cst[8] = {};

    for (int t = 0; t < Tn; ++t) {
        const int q = t & 1;
        // -- stage x(t) regs -> X[q] --
        {
            float e[8] = {gA.x, gA.y, gA.z, gA.w, gB.x, gB.y, gB.z, gB.w};
#pragma unroll
            for (int jj = 0; jj < 8; ++jj)
                lds.X[q][sch * 8 + jj][wave][sd] = e[jj];
        }
        // -- write h(t-1) -> H[q] (zeros at t=0) --
#pragma unroll
        for (int hh = 0; hh < 2; ++hh)
#pragma unroll
            for (int r = 0; r < 4; ++r)
                lds.H[q][wave][kg * 4 + r][hh * 16 + l16] = hD[hh * 4 + r];
        // -- prefetch x(t+1) --
        if (t + 1 < Tn) {
            gA = *(const float4*)(xb + (size_t)(t + 1) * DC);
            gB = *(const float4*)(xb + (size_t)(t + 1) * DC + 4);
        }
        __syncthreads();

        // -- sp store h(t-1): waves 0..3, 256B-contiguous per 16 lanes --
        if (wave < 4 && t > 0) {
#pragma unroll
            for (int bg = 0; bg < 4; ++bg) {
                int b_loc = bg * 4 + bsub;
                const float* hp = &lds.H[q][cell_l][b_loc][wave * 8];
                float4 e0 = *(const float4*)hp;
                float4 e1 = *(const float4*)(hp + 4);
                int4 sv = {(int)cvt_pk(e0.x, e0.y), (int)cvt_pk(e0.z, e0.w),
                           (int)cvt_pk(e1.x, e1.y), (int)cvt_pk(e1.z, e1.w)};
                size_t plane = (size_t)(gb0 + b_loc) * 96 + (size_t)(t - 1) * 4 + wave;
                *(int4*)(sp + (plane * PPXN + ppx0 + cell_l) * 8) = sv;
            }
        }

        // -- fragments (cell = wave, rows b = l16, k = kg*8..+7) --
        U8 xfh, xfl, hfh, hfl;
        {
            const float* xp = &lds.X[q][wave][l16][kg * 8];
            float4 a0 = *(const float4*)xp;
            float4 a1 = *(const float4*)(xp + 4);
            float e[8] = {a0.x, a0.y, a0.z, a0.w, a1.x, a1.y, a1.z, a1.w};
#pragma unroll
            for (int pp = 0; pp < 4; ++pp) {
                unsigned a = cvt_pk(e[2*pp], e[2*pp+1]);
                xfh.u[pp] = a;
                xfl.u[pp] = cvt_pk(e[2*pp] - lo16f(a), e[2*pp+1] - hi16f(a));
            }
            const float* hp = &lds.H[q][wave][l16][kg * 8];
            float4 b0 = *(const float4*)hp;
            float4 b1 = *(const float4*)(hp + 4);
            float f[8] = {b0.x, b0.y, b0.z, b0.w, b1.x, b1.y, b1.z, b1.w};
#pragma unroll
            for (int pp = 0; pp < 4; ++pp) {
                unsigned a = cvt_pk(f[2*pp], f[2*pp+1]);
                hfh.u[pp] = a;
                hfl.u[pp] = cvt_pk(f[2*pp] - lo16f(a), f[2*pp+1] - hi16f(a));
            }
        }

        // -- MFMA: 8 q-tiles x 6-term split --
        f32x4 acc[8];
#pragma unroll
        for (int q8 = 0; q8 < 8; ++q8) {
            f32x4 a = {biasr[q8], biasr[q8], biasr[q8], biasr[q8]};
            a = __builtin_amdgcn_mfma_f32_16x16x32_bf16(xfh.v, wihh[q8].v, a, 0, 0, 0);
            a = __builtin_amdgcn_mfma_f32_16x16x32_bf16(xfl.v, wihh[q8].v, a, 0, 0, 0);
            a = __builtin_amdgcn_mfma_f32_16x16x32_bf16(xfh.v, wihl[q8].v, a, 0, 0, 0);
            a = __builtin_amdgcn_mfma_f32_16x16x32_bf16(hfh.v, whhh[q8].v, a, 0, 0, 0);
            a = __builtin_amdgcn_mfma_f32_16x16x32_bf16(hfl.v, whhh[q8].v, a, 0, 0, 0);
            a = __builtin_amdgcn_mfma_f32_16x16x32_bf16(hfh.v, whhl[q8].v, a, 0, 0, 0);
            acc[q8] = a;
        }

        // -- gates: col = q*16+l16 -> gate = q>>1, h = (q&1)*16+l16 --
#pragma unroll
        for (int hh = 0; hh < 2; ++hh)
#pragma unroll
            for (int r = 0; r < 4; ++r) {
                float gi = acc[0 + hh][r], gf = acc[2 + hh][r];
                float gg = acc[4 + hh][r], go = acc[6 + hh][r];
                float ig = rcp_(1.f + exp2_(-gi));
                float fg = rcp_(1.f + exp2_(-gf));
                float gt = 1.f - 2.f * rcp_(1.f + exp2_(gg + gg));
                float og = rcp_(1.f + exp2_(-go));
                float c  = fg * cst[hh * 4 + r] + ig * gt;
                cst[hh * 4 + r] = c;
                float tc = 1.f - 2.f * rcp_(1.f + exp2_((2.f * SCALE) * c));
                hD[hh * 4 + r] = og * tc;
            }
    }

    // ---- epilogue: flush h(Tn-1) ----
#pragma unroll
    for (int hh = 0; hh < 2; ++hh)
#pragma unroll
        for (int r = 0; r < 4; ++r)
            lds.H[0][wave][kg * 4 + r][hh * 16 + l16] = hD[hh * 4 + r];
    __syncthreads();
    if (wave < 4) {
#pragma unroll
        for (int bg = 0; bg < 4; ++bg) {
            int b_loc = bg * 4 + bsub;
            const float* hp = &lds.H[0][cell_l][b_loc][wave * 8];
            float4 e0 = *(const float4*)hp;
            float4 e1 = *(const float4*)(hp + 4);
            int4 sv = {(int)cvt_pk(e0.x, e0.y), (int)cvt_pk(e0.z, e0.w),
                       (int)cvt_pk(e1.x, e1.y), (int)cvt_pk(e1.z, e1.w)};
            size_t plane = (size_t)(gb0 + b_loc) * 96 + (size_t)(Tn - 1) * 4 + wave;
            *(int4*)(sp + (plane * PPXN + ppx0 + cell_l) * 8) = sv;
        }
    }
}

// ---- conv: 768 blocks (b,t) x 512 thr, 2 px/thread, fp32 math, fused sigmoid ----
__global__ __launch_bounds__(512, 4)
void conv_k4(const unsigned short* __restrict__ sp,
             const float* __restrict__ cw,
             const float* __restrict__ cb,
             float* __restrict__ out)
{
    __shared__ float wlds[9][32];
    const int tid = threadIdx.x;
    const int img = blockIdx.x;
    if (tid < 288) wlds[tid >> 5][tid & 31] = cw[(tid & 31) * 9 + (tid >> 5)];
    __syncthreads();
    const float bias = cb[0];
    float acc[2] = {bias, bias};
    int ppx[2];
#pragma unroll
    for (int pk = 0; pk < 2; ++pk) {
        int px = tid + pk * 512;
        ppx[pk] = ((px >> 5) + 1) * MP + (px & 31) + 1;
    }
#pragma unroll
    for (int hc = 0; hc < 4; ++hc) {
        float4 wa[9], wb[9];
#pragma unroll
        for (int tap = 0; tap < 9; ++tap) {
            wa[tap] = *(const float4*)&wlds[tap][hc * 8];
            wb[tap] = *(const float4*)&wlds[tap][hc * 8 + 4];
        }
        const unsigned short* plane = sp + (size_t)(img * 4 + hc) * (PPXN * 8);
#pragma unroll
        for (int pk = 0; pk < 2; ++pk) {
            const unsigned short* base = plane + (size_t)ppx[pk] * 8;
            float a = acc[pk];
#pragma unroll
            for (int dm = -1; dm <= 1; ++dm)
#pragma unroll
                for (int dn = -1; dn <= 1; ++dn) {
                    const int tap = (dm + 1) * 3 + (dn + 1);
                    int4 v = *(const int4*)(base + (dm * MP + dn) * 8);
                    float4 w0 = wa[tap], w1 = wb[tap];
                    a = fmaf(lo16f((unsigned)v.x), w0.x, a);
                    a = fmaf(hi16f((unsigned)v.x), w0.y, a);
                    a = fmaf(lo16f((unsigned)v.y), w0.z, a);
                    a = fmaf(hi16f((unsigned)v.y), w0.w, a);
                    a = fmaf(lo16f((unsigned)v.z), w1.x, a);
                    a = fmaf(hi16f((unsigned)v.z), w1.y, a);
                    a = fmaf(lo16f((unsigned)v.w), w1.z, a);
                    a = fmaf(hi16f((unsigned)v.w), w1.w, a);
                }
            acc[pk] = a;
        }
    }
#pragma unroll
    for (int pk = 0; pk < 2; ++pk)
        out[(size_t)img * 1024 + tid + pk * 512] = rcp_(1.f + exp2_(-SCALE * acc[pk]));
}

extern "C" void kernel_launch(void* const* d_in, const int* in_sizes, int n_in,
                              void* d_out, int out_size, void* d_ws, size_t ws_size,
                              hipStream_t stream) {
    const float* x   = (const float*)d_in[0];
    const float* Wih = (const float*)d_in[1];
    const float* Whh = (const float*)d_in[2];
    const float* bih = (const float*)d_in[3];
    const float* bhh = (const float*)d_in[4];
    const float* cw  = (const float*)d_in[5];
    const float* cb  = (const float*)d_in[6];
    float* out = (float*)d_out;
    unsigned short* sp = (unsigned short*)d_ws;  // bf16 (B,T, chunk4, 34,34, 8ch)

    zero_halo<<<792, 512, 0, stream>>>(sp);
    lstm_k8<<<128, 1024, 0, stream>>>(x, Wih, Whh, bih, bhh, sp);
    conv_k4<<<Bn * Tn, 512, 0, stream>>>(sp, cw, cb, out);
}

// Round 9
// 118.687 us; speedup vs baseline: 3.7715x; 3.7715x over previous
//
#include <hip/hip_runtime.h>

#define Bn 32
#define Tn 24
#define Dn 32
#define Hn 32
#define Cn 1024
#define DC (Dn*Cn)      /* 32768 */
#define TDC (Tn*Dn*Cn)  /* 786432 */
#define MP 34
#define PPXN (MP*MP)    /* 1156 */
#define IMGS (MP*MP*32) /* shorts per image (4 planes * 1156 * 8) */
#define SCALE 1.442695041f

#define XSTR 576   /* X cell stride (16*36) floats */
#define HSTR 592   /* H cell stride (16*36+16) floats */

typedef __attribute__((ext_vector_type(8))) short bf16x8;
typedef __attribute__((ext_vector_type(4))) float f32x4;

union U8 { unsigned u[4]; int4 i; bf16x8 v; };

__device__ __forceinline__ unsigned cvt_pk(float lo, float hi) {
    unsigned r; asm("v_cvt_pk_bf16_f32 %0, %1, %2" : "=v"(r) : "v"(lo), "v"(hi)); return r;
}
__device__ __forceinline__ float lo16f(unsigned u) { return __builtin_bit_cast(float, u << 16); }
__device__ __forceinline__ float hi16f(unsigned u) { return __builtin_bit_cast(float, u & 0xffff0000u); }
__device__ __forceinline__ float rcp_(float x) { return __builtin_amdgcn_rcpf(x); }
__device__ __forceinline__ float exp2_(float x) { return __builtin_amdgcn_exp2f(x); }

struct __align__(16) LdsL {
    float X[2][8 * XSTR];   // [buf][c*576 + b*36 + d] fp32
    float H[2][8 * HSTR];   // [buf][c*592 + b*36 + h] fp32
};

// ---- zero the 1-px halo ring of every (img, chunk) plane ----
__global__ __launch_bounds__(512)
void zero_halo(unsigned short* __restrict__ sp) {
    int gid = blockIdx.x * 512 + threadIdx.x;
    if (gid >= 3072 * 132) return;
    int plane = gid / 132;
    int r = gid - plane * 132;
    int m, n;
    if (r < 34)       { m = 0;      n = r; }
    else if (r < 68)  { m = 33;     n = r - 34; }
    else if (r < 100) { m = r - 67; n = 0; }
    else              { m = r - 99; n = 33; }
    int4 z = {0, 0, 0, 0};
    *(int4*)(sp + ((size_t)plane * PPXN + m * MP + n) * 8) = z;
}

// ---- LSTM: grid 256 = 128 cellgroups(8 cells) x 2 bslices; 1024 thr = 16 waves ----
// wave w: cell ci = w>>1 (0..7), gate-half gh = w&1. W per wave = 64 u32 (no spill).
__global__ __launch_bounds__(1024, 4)
void lstm_k9(const float* __restrict__ x,
             const float* __restrict__ Wih,
             const float* __restrict__ Whh,
             const float* __restrict__ bih,
             const float* __restrict__ bhh,
             unsigned short* __restrict__ sp)
{
    __shared__ LdsL lds;
    const int tid  = threadIdx.x;
    const int lane = tid & 63;
    const int wave = tid >> 6;
    const int ci   = wave >> 1;
    const int gh   = wave & 1;
    const int l16  = lane & 15;
    const int kg   = lane >> 4;
    const int bid  = blockIdx.x;
    const int xcd  = bid & 7, r2 = bid >> 3;       // r2 0..31
    const int cg   = xcd * 16 + (r2 & 15);          // 0..127, XCD-contiguous
    const int bs   = r2 >> 4;                       // 0..1
    const int cellbase = cg * 8;
    const int cell = cellbase + ci;
    const int gb0  = bs * 16;

    // ---- W fragments: 4 q-tiles (gate types) x 16 cols, split hi/lo, pre-scaled ----
    U8 wihh[4], wihl[4], whhh[4], whhl[4];
    float biasr[4];
#pragma unroll
    for (int q = 0; q < 4; ++q) {
        const int g = q * 32 + gh * 16 + l16;
        const float* wp = Wih + (size_t)cell * 4096 + g * 32 + kg * 8;
        const float* hp = Whh + (size_t)cell * 4096 + g * 32 + kg * 8;
        float wv[8], hv[8];
#pragma unroll
        for (int j = 0; j < 8; ++j) { wv[j] = wp[j] * SCALE; hv[j] = hp[j] * SCALE; }
#pragma unroll
        for (int p = 0; p < 4; ++p) {
            unsigned a = cvt_pk(wv[2*p], wv[2*p+1]);
            wihh[q].u[p] = a;
            wihl[q].u[p] = cvt_pk(wv[2*p] - lo16f(a), wv[2*p+1] - hi16f(a));
            unsigned b = cvt_pk(hv[2*p], hv[2*p+1]);
            whhh[q].u[p] = b;
            whhl[q].u[p] = cvt_pk(hv[2*p] - lo16f(b), hv[2*p+1] - hi16f(b));
        }
        biasr[q] = (bih[cell * 128 + g] + bhh[cell * 128 + g]) * SCALE;
    }

    // ---- x staging: wave = batch row b; lane -> (d = lane>>1, cq = lane&1) float4 ----
    const int sd = lane >> 1, cq = lane & 1;
    const float* xb = x + (size_t)(gb0 + wave) * TDC + (size_t)sd * Cn + cellbase + cq * 4;
    float4 gX = *(const float4*)xb;

    // ---- sp store map (waves 0..3 = chunk w): lane -> (cl = lane&7, bsub = lane>>3) ----
    const int cl = lane & 7, bsub = lane >> 3;
    const int sm = cg >> 2, n0 = (cg & 3) * 8;
    const int ppx0 = (sm + 1) * MP + n0 + 1;

    float hD[4] = {}, cst[4] = {};

    for (int t = 0; t < Tn; ++t) {
        const int p = t & 1;
        // -- phase 1: stage x(t) -> X[p]; write h(t-1) -> H[p]; prefetch x(t+1) --
        {
            float e[4] = {gX.x, gX.y, gX.z, gX.w};
#pragma unroll
            for (int i = 0; i < 4; ++i)
                lds.X[p][(cq * 4 + i) * XSTR + wave * 36 + sd] = e[i];
        }
#pragma unroll
        for (int r = 0; r < 4; ++r)
            lds.H[p][ci * HSTR + (kg * 4 + r) * 36 + gh * 16 + l16] = hD[r];
        if (t + 1 < Tn)
            gX = *(const float4*)(xb + (size_t)(t + 1) * DC);
        __syncthreads();

        // -- phase 2a: sp store h(t-1) (waves 0..3), 128B-contiguous per 8 lanes --
        if (wave < 4 && t > 0) {
#pragma unroll
            for (int bg = 0; bg < 2; ++bg) {
                int b_loc = bg * 8 + bsub;
                const float* hp = &lds.H[p][cl * HSTR + b_loc * 36 + wave * 8];
                float e0 = hp[0], e1 = hp[1], e2 = hp[2], e3 = hp[3];
                float e4 = hp[4], e5 = hp[5], e6 = hp[6], e7 = hp[7];
                int4 sv = {(int)cvt_pk(e0, e1), (int)cvt_pk(e2, e3),
                           (int)cvt_pk(e4, e5), (int)cvt_pk(e6, e7)};
                size_t plane = (size_t)(gb0 + b_loc) * 96 + (size_t)(t - 1) * 4 + wave;
                *(int4*)(sp + (plane * PPXN + ppx0 + cl) * 8) = sv;
            }
        }

        // -- phase 2b: fragments (rows b = l16, k = kg*8..+7) --
        U8 xfh, xfl, hfh, hfl;
        {
            const float* xp = &lds.X[p][ci * XSTR + l16 * 36 + kg * 8];
            float4 a0 = *(const float4*)xp;
            float4 a1 = *(const float4*)(xp + 4);
            float e[8] = {a0.x, a0.y, a0.z, a0.w, a1.x, a1.y, a1.z, a1.w};
#pragma unroll
            for (int pp = 0; pp < 4; ++pp) {
                unsigned a = cvt_pk(e[2*pp], e[2*pp+1]);
                xfh.u[pp] = a;
                xfl.u[pp] = cvt_pk(e[2*pp] - lo16f(a), e[2*pp+1] - hi16f(a));
            }
            const float* hq = &lds.H[p][ci * HSTR + l16 * 36 + kg * 8];
            float4 b0 = *(const float4*)hq;
            float4 b1 = *(const float4*)(hq + 4);
            float f[8] = {b0.x, b0.y, b0.z, b0.w, b1.x, b1.y, b1.z, b1.w};
#pragma unroll
            for (int pp = 0; pp < 4; ++pp) {
                unsigned a = cvt_pk(f[2*pp], f[2*pp+1]);
                hfh.u[pp] = a;
                hfl.u[pp] = cvt_pk(f[2*pp] - lo16f(a), f[2*pp+1] - hi16f(a));
            }
        }

        // -- phase 2c: MFMA, 4 q-tiles x 6-term split --
        f32x4 acc[4];
#pragma unroll
        for (int q = 0; q < 4; ++q) {
            f32x4 a = {biasr[q], biasr[q], biasr[q], biasr[q]};
            a = __builtin_amdgcn_mfma_f32_16x16x32_bf16(xfh.v, wihh[q].v, a, 0, 0, 0);
            a = __builtin_amdgcn_mfma_f32_16x16x32_bf16(xfl.v, wihh[q].v, a, 0, 0, 0);
            a = __builtin_amdgcn_mfma_f32_16x16x32_bf16(xfh.v, wihl[q].v, a, 0, 0, 0);
            a = __builtin_amdgcn_mfma_f32_16x16x32_bf16(hfh.v, whhh[q].v, a, 0, 0, 0);
            a = __builtin_amdgcn_mfma_f32_16x16x32_bf16(hfl.v, whhh[q].v, a, 0, 0, 0);
            a = __builtin_amdgcn_mfma_f32_16x16x32_bf16(hfh.v, whhl[q].v, a, 0, 0, 0);
            acc[q] = a;
        }

        // -- phase 2d: gates (pre-scaled by log2e), rows b = kg*4+r --
#pragma unroll
        for (int r = 0; r < 4; ++r) {
            float gi = acc[0][r], gf = acc[1][r];
            float gg = acc[2][r], go = acc[3][r];
            float ig = rcp_(1.f + exp2_(-gi));
            float fg = rcp_(1.f + exp2_(-gf));
            float gt = 1.f - 2.f * rcp_(1.f + exp2_(gg + gg));
            float og = rcp_(1.f + exp2_(-go));
            float c  = fg * cst[r] + ig * gt;
            cst[r] = c;
            float tc = 1.f - 2.f * rcp_(1.f + exp2_((2.f * SCALE) * c));
            hD[r] = og * tc;
        }
    }

    // ---- epilogue: flush h(Tn-1) ----
#pragma unroll
    for (int r = 0; r < 4; ++r)
        lds.H[0][ci * HSTR + (kg * 4 + r) * 36 + gh * 16 + l16] = hD[r];
    __syncthreads();
    if (wave < 4) {
#pragma unroll
        for (int bg = 0; bg < 2; ++bg) {
            int b_loc = bg * 8 + bsub;
            const float* hp = &lds.H[0][cl * HSTR + b_loc * 36 + wave * 8];
            float e0 = hp[0], e1 = hp[1], e2 = hp[2], e3 = hp[3];
            float e4 = hp[4], e5 = hp[5], e6 = hp[6], e7 = hp[7];
            int4 sv = {(int)cvt_pk(e0, e1), (int)cvt_pk(e2, e3),
                       (int)cvt_pk(e4, e5), (int)cvt_pk(e6, e7)};
            size_t plane = (size_t)(gb0 + b_loc) * 96 + (size_t)(Tn - 1) * 4 + wave;
            *(int4*)(sp + (plane * PPXN + ppx0 + cl) * 8) = sv;
        }
    }
}

// ---- conv: 768 blocks (b,t) x 512 thr, 2 px/thread, fp32 math, fused sigmoid ----
__global__ __launch_bounds__(512, 4)
void conv_k4(const unsigned short* __restrict__ sp,
             const float* __restrict__ cw,
             const float* __restrict__ cb,
             float* __restrict__ out)
{
    __shared__ float wlds[9][32];
    const int tid = threadIdx.x;
    const int img = blockIdx.x;
    if (tid < 288) wlds[tid >> 5][tid & 31] = cw[(tid & 31) * 9 + (tid >> 5)];
    __syncthreads();
    const float bias = cb[0];
    float acc[2] = {bias, bias};
    int ppx[2];
#pragma unroll
    for (int pk = 0; pk < 2; ++pk) {
        int px = tid + pk * 512;
        ppx[pk] = ((px >> 5) + 1) * MP + (px & 31) + 1;
    }
#pragma unroll
    for (int hc = 0; hc < 4; ++hc) {
        float4 wa[9], wb[9];
#pragma unroll
        for (int tap = 0; tap < 9; ++tap) {
            wa[tap] = *(const float4*)&wlds[tap][hc * 8];
            wb[tap] = *(const float4*)&wlds[tap][hc * 8 + 4];
        }
        const unsigned short* plane = sp + (size_t)(img * 4 + hc) * (PPXN * 8);
#pragma unroll
        for (int pk = 0; pk < 2; ++pk) {
            const unsigned short* base = plane + (size_t)ppx[pk] * 8;
            float a = acc[pk];
#pragma unroll
            for (int dm = -1; dm <= 1; ++dm)
#pragma unroll
                for (int dn = -1; dn <= 1; ++dn) {
                    const int tap = (dm + 1) * 3 + (dn + 1);
                    int4 v = *(const int4*)(base + (dm * MP + dn) * 8);
                    float4 w0 = wa[tap], w1 = wb[tap];
                    a = fmaf(lo16f((unsigned)v.x), w0.x, a);
                    a = fmaf(hi16f((unsigned)v.x), w0.y, a);
                    a = fmaf(lo16f((unsigned)v.y), w0.z, a);
                    a = fmaf(hi16f((unsigned)v.y), w0.w, a);
                    a = fmaf(lo16f((unsigned)v.z), w1.x, a);
                    a = fmaf(hi16f((unsigned)v.z), w1.y, a);
                    a = fmaf(lo16f((unsigned)v.w), w1.z, a);
                    a = fmaf(hi16f((unsigned)v.w), w1.w, a);
                }
            acc[pk] = a;
        }
    }
#pragma unroll
    for (int pk = 0; pk < 2; ++pk)
        out[(size_t)img * 1024 + tid + pk * 512] = rcp_(1.f + exp2_(-SCALE * acc[pk]));
}

extern "C" void kernel_launch(void* const* d_in, const int* in_sizes, int n_in,
                              void* d_out, int out_size, void* d_ws, size_t ws_size,
                              hipStream_t stream) {
    const float* x   = (const float*)d_in[0];
    const float* Wih = (const float*)d_in[1];
    const float* Whh = (const float*)d_in[2];
    const float* bih = (const float*)d_in[3];
    const float* bhh = (const float*)d_in[4];
    const float* cw  = (const float*)d_in[5];
    const float* cb  = (const float*)d_in[6];
    float* out = (float*)d_out;
    unsigned short* sp = (unsigned short*)d_ws;  // bf16 (B,T, chunk4, 34,34, 8ch)

    zero_halo<<<792, 512, 0, stream>>>(sp);
    lstm_k9<<<256, 1024, 0, stream>>>(x, Wih, Whh, bih, bhh, sp);
    conv_k4<<<Bn * Tn, 512, 0, stream>>>(sp, cw, cb, out);
}

// Round 10
// 101.566 us; speedup vs baseline: 4.4073x; 1.1686x over previous
//
#include <hip/hip_runtime.h>

#define Bn 32
#define Tn 24
#define Dn 32
#define Hn 32
#define Cn 1024
#define DC (Dn*Cn)      /* 32768 */
#define TDC (Tn*Dn*Cn)  /* 786432 */
#define MP 34
#define PPXN (MP*MP)    /* 1156 */
#define IMGS (MP*MP*32) /* shorts per image (4 planes * 1156 * 8) */
#define SCALE 1.442695041f

typedef __attribute__((ext_vector_type(8))) short bf16x8;
typedef __attribute__((ext_vector_type(4))) float f32x4;

__device__ __forceinline__ unsigned cvt_pk(float lo, float hi) {
    unsigned r; asm("v_cvt_pk_bf16_f32 %0, %1, %2" : "=v"(r) : "v"(lo), "v"(hi)); return r;
}
__device__ __forceinline__ float lo16f(unsigned u) { return __builtin_bit_cast(float, u << 16); }
__device__ __forceinline__ float hi16f(unsigned u) { return __builtin_bit_cast(float, u & 0xffff0000u); }
__device__ __forceinline__ float rcp_(float x) { return __builtin_amdgcn_rcpf(x); }
__device__ __forceinline__ float exp2_(float x) { return __builtin_amdgcn_exp2f(x); }
__device__ __forceinline__ bf16x8 bc(int4 v) { return __builtin_bit_cast(bf16x8, v); }

struct __align__(16) LdsT {
    unsigned short Xh[2][2][32][48];  // [buf][cell][b][d pad48] hi plane
    unsigned short Xl[2][2][32][48];  // lo plane
    float Hf[2][2][32][36];           // [buf][cell][b][hid pad36] fp32 h
};

// ---- zero the 1-px halo ring of every (img, chunk) plane ----
__global__ __launch_bounds__(512)
void zero_halo(unsigned short* __restrict__ sp) {
    int gid = blockIdx.x * 512 + threadIdx.x;
    if (gid >= 3072 * 132) return;
    int plane = gid / 132;
    int r = gid - plane * 132;
    int m, n;
    if (r < 34)       { m = 0;      n = r; }
    else if (r < 68)  { m = 33;     n = r - 34; }
    else if (r < 100) { m = r - 67; n = 0; }
    else              { m = r - 99; n = 33; }
    int4 z = {0, 0, 0, 0};
    *(int4*)(sp + ((size_t)plane * PPXN + m * MP + n) * 8) = z;
}

// ---- LSTM: grid 512 x 256 thr. Block owns 2 cells x 32 batch.
// wave w: cell ci = w>>1, gate-half half = w&1. mt-tiles processed sequentially.
__global__ __launch_bounds__(256) __attribute__((amdgpu_waves_per_eu(3, 3)))
void lstm_k10(const float* __restrict__ x,
              const float* __restrict__ Wih,
              const float* __restrict__ Whh,
              const float* __restrict__ bih,
              const float* __restrict__ bhh,
              unsigned short* __restrict__ sp)
{
    __shared__ LdsT lds;
    const int tid  = threadIdx.x;
    const int lane = tid & 63;
    const int wave = tid >> 6;
    const int ci   = wave >> 1;
    const int half = wave & 1;
    const int l16  = lane & 15;
    const int kg   = lane >> 4;
    const int bid  = blockIdx.x;
    const int cellbase = (bid & 7) * 128 + (bid >> 3) * 2;  // XCD-contiguous cells
    const int cell = cellbase + ci;

    // ---- W fragments (int4, SROA-friendly), split hi/lo, pre-scaled by log2e ----
    int4 wihh[4], wihl[4], whhh[4], whhl[4];
    float biasr[4];
#pragma unroll
    for (int q = 0; q < 4; ++q) {
        const int g = q * 32 + half * 16 + l16;
        const float* wp = Wih + (size_t)cell * 4096 + g * 32 + kg * 8;
        const float* hp = Whh + (size_t)cell * 4096 + g * 32 + kg * 8;
        float wv[8], hv[8];
#pragma unroll
        for (int j = 0; j < 8; ++j) { wv[j] = wp[j] * SCALE; hv[j] = hp[j] * SCALE; }
        unsigned a0 = cvt_pk(wv[0], wv[1]), a1 = cvt_pk(wv[2], wv[3]);
        unsigned a2 = cvt_pk(wv[4], wv[5]), a3 = cvt_pk(wv[6], wv[7]);
        wihh[q] = int4{(int)a0, (int)a1, (int)a2, (int)a3};
        wihl[q] = int4{(int)cvt_pk(wv[0] - lo16f(a0), wv[1] - hi16f(a0)),
                       (int)cvt_pk(wv[2] - lo16f(a1), wv[3] - hi16f(a1)),
                       (int)cvt_pk(wv[4] - lo16f(a2), wv[5] - hi16f(a2)),
                       (int)cvt_pk(wv[6] - lo16f(a3), wv[7] - hi16f(a3))};
        unsigned b0 = cvt_pk(hv[0], hv[1]), b1 = cvt_pk(hv[2], hv[3]);
        unsigned b2 = cvt_pk(hv[4], hv[5]), b3 = cvt_pk(hv[6], hv[7]);
        whhh[q] = int4{(int)b0, (int)b1, (int)b2, (int)b3};
        whhl[q] = int4{(int)cvt_pk(hv[0] - lo16f(b0), hv[1] - hi16f(b0)),
                       (int)cvt_pk(hv[2] - lo16f(b1), hv[3] - hi16f(b1)),
                       (int)cvt_pk(hv[4] - lo16f(b2), hv[5] - hi16f(b2)),
                       (int)cvt_pk(hv[6] - lo16f(b3), hv[7] - hi16f(b3))};
        biasr[q] = (bih[cell * 128 + g] + bhh[cell * 128 + g]) * SCALE;
    }

    // ---- staging map: thread -> (b = tid>>3, d0 = (tid&7)*4), float2 covers 2 cells ----
    const int sb = tid >> 3;
    const int d0 = (tid & 7) * 4;
    const float* xg0 = x + (size_t)sb * TDC + (size_t)d0 * Cn + cellbase;

    // sp store base (rows b = half*16 + l16, chunk kg)
    const int sm = cell >> 5, sn = cell & 31;
    const int ppx = (sm + 1) * MP + (sn + 1);
    unsigned short* spb = sp + ((size_t)(half * 16 + l16) * Tn * 4 + kg) * (PPXN * 8)
                             + (size_t)ppx * 8;

    float hD[8] = {};   // h(t-1) D-layout: rows mt*16 + kg*4 + r
    float cst[8] = {};
    float2 nx[4];
#pragma unroll
    for (int k = 0; k < 4; ++k) nx[k] = *(const float2*)(xg0 + k * Cn);

    for (int t = 0; t < Tn; ++t) {
        const int bufi = t & 1;
        // -- stage x(t): split hi/lo, b64 writes --
#pragma unroll
        for (int cc = 0; cc < 2; ++cc) {
            float f0 = cc ? nx[0].y : nx[0].x;
            float f1 = cc ? nx[1].y : nx[1].x;
            float f2 = cc ? nx[2].y : nx[2].x;
            float f3 = cc ? nx[3].y : nx[3].x;
            unsigned a0 = cvt_pk(f0, f1), a1 = cvt_pk(f2, f3);
            float r0 = f0 - lo16f(a0), r1 = f1 - hi16f(a0);
            float r2 = f2 - lo16f(a1), r3 = f3 - hi16f(a1);
            int2 hi2 = {(int)a0, (int)a1};
            int2 lo2 = {(int)cvt_pk(r0, r1), (int)cvt_pk(r2, r3)};
            *(int2*)&lds.Xh[bufi][cc][sb][d0] = hi2;
            *(int2*)&lds.Xl[bufi][cc][sb][d0] = lo2;
        }
        // -- write h(t-1) -> Hf[bufi] --
#pragma unroll
        for (int i = 0; i < 8; ++i) {
            int mt = i >> 2, r = i & 3;
            lds.Hf[bufi][ci][mt * 16 + kg * 4 + r][half * 16 + l16] = hD[i];
        }
        // -- prefetch x(t+1) --
        if (t < Tn - 1) {
#pragma unroll
            for (int k = 0; k < 4; ++k)
                nx[k] = *(const float2*)(xg0 + (size_t)(t + 1) * DC + k * Cn);
        }
        __syncthreads();

        unsigned sphi0 = 0, sphi1 = 0, sphi2 = 0, sphi3 = 0;
        // -- mt tiles sequential (halves frag register pressure) --
#pragma unroll
        for (int mt = 0; mt < 2; ++mt) {
            int4 xfh = *(const int4*)&lds.Xh[bufi][ci][mt * 16 + l16][kg * 8];
            int4 xfl = *(const int4*)&lds.Xl[bufi][ci][mt * 16 + l16][kg * 8];
            const float* hp = &lds.Hf[bufi][ci][mt * 16 + l16][kg * 8];
            float4 ha = *(const float4*)hp;
            float4 hb = *(const float4*)(hp + 4);
            unsigned p0 = cvt_pk(ha.x, ha.y), p1 = cvt_pk(ha.z, ha.w);
            unsigned p2 = cvt_pk(hb.x, hb.y), p3 = cvt_pk(hb.z, hb.w);
            int4 hfh = int4{(int)p0, (int)p1, (int)p2, (int)p3};
            int4 hfl = int4{(int)cvt_pk(ha.x - lo16f(p0), ha.y - hi16f(p0)),
                            (int)cvt_pk(ha.z - lo16f(p1), ha.w - hi16f(p1)),
                            (int)cvt_pk(hb.x - lo16f(p2), hb.y - hi16f(p2)),
                            (int)cvt_pk(hb.z - lo16f(p3), hb.w - hi16f(p3))};
            if (mt == half) { sphi0 = p0; sphi1 = p1; sphi2 = p2; sphi3 = p3; }

            f32x4 acc[4];
#pragma unroll
            for (int q = 0; q < 4; ++q) {
                f32x4 a = {biasr[q], biasr[q], biasr[q], biasr[q]};
                a = __builtin_amdgcn_mfma_f32_16x16x32_bf16(bc(xfh), bc(wihh[q]), a, 0, 0, 0);
                a = __builtin_amdgcn_mfma_f32_16x16x32_bf16(bc(xfl), bc(wihh[q]), a, 0, 0, 0);
                a = __builtin_amdgcn_mfma_f32_16x16x32_bf16(bc(xfh), bc(wihl[q]), a, 0, 0, 0);
                a = __builtin_amdgcn_mfma_f32_16x16x32_bf16(bc(hfh), bc(whhh[q]), a, 0, 0, 0);
                a = __builtin_amdgcn_mfma_f32_16x16x32_bf16(bc(hfl), bc(whhh[q]), a, 0, 0, 0);
                a = __builtin_amdgcn_mfma_f32_16x16x32_bf16(bc(hfh), bc(whhl[q]), a, 0, 0, 0);
                acc[q] = a;
            }
            // gates for this mt tile
#pragma unroll
            for (int r = 0; r < 4; ++r) {
                float gi = acc[0][r], gf = acc[1][r];
                float gg = acc[2][r], go = acc[3][r];
                float ig = rcp_(1.f + exp2_(-gi));
                float fg = rcp_(1.f + exp2_(-gf));
                float gt = 1.f - 2.f * rcp_(1.f + exp2_(gg + gg));
                float og = rcp_(1.f + exp2_(-go));
                float c  = fg * cst[mt * 4 + r] + ig * gt;
                cst[mt * 4 + r] = c;
                float tc = 1.f - 2.f * rcp_(1.f + exp2_((2.f * SCALE) * c));
                hD[mt * 4 + r] = og * tc;
            }
        }

        // -- store h(t-1) bf16-hi to sp --
        if (t > 0) {
            int4 sv = {(int)sphi0, (int)sphi1, (int)sphi2, (int)sphi3};
            *(int4*)(spb + (size_t)(t - 1) * IMGS) = sv;
        }
    }

    // ---- epilogue: flush h(Tn-1) ----
#pragma unroll
    for (int i = 0; i < 8; ++i) {
        int mt = i >> 2, r = i & 3;
        lds.Hf[0][ci][mt * 16 + kg * 4 + r][half * 16 + l16] = hD[i];
    }
    __syncthreads();
    {
        const float* hp = &lds.Hf[0][ci][half * 16 + l16][kg * 8];
        float4 ha = *(const float4*)hp;
        float4 hb = *(const float4*)(hp + 4);
        int4 sv = {(int)cvt_pk(ha.x, ha.y), (int)cvt_pk(ha.z, ha.w),
                   (int)cvt_pk(hb.x, hb.y), (int)cvt_pk(hb.z, hb.w)};
        *(int4*)(spb + (size_t)(Tn - 1) * IMGS) = sv;
    }
}

// ---- conv: 768 blocks (b,t) x 512 thr, 2 px/thread, fp32 math, fused sigmoid ----
__global__ __launch_bounds__(512, 4)
void conv_k4(const unsigned short* __restrict__ sp,
             const float* __restrict__ cw,
             const float* __restrict__ cb,
             float* __restrict__ out)
{
    __shared__ float wlds[9][32];
    const int tid = threadIdx.x;
    const int img = blockIdx.x;
    if (tid < 288) wlds[tid >> 5][tid & 31] = cw[(tid & 31) * 9 + (tid >> 5)];
    __syncthreads();
    const float bias = cb[0];
    float acc[2] = {bias, bias};
    int ppx[2];
#pragma unroll
    for (int pk = 0; pk < 2; ++pk) {
        int px = tid + pk * 512;
        ppx[pk] = ((px >> 5) + 1) * MP + (px & 31) + 1;
    }
#pragma unroll
    for (int hc = 0; hc < 4; ++hc) {
        float4 wa[9], wb[9];
#pragma unroll
        for (int tap = 0; tap < 9; ++tap) {
            wa[tap] = *(const float4*)&wlds[tap][hc * 8];
            wb[tap] = *(const float4*)&wlds[tap][hc * 8 + 4];
        }
        const unsigned short* plane = sp + (size_t)(img * 4 + hc) * (PPXN * 8);
#pragma unroll
        for (int pk = 0; pk < 2; ++pk) {
            const unsigned short* base = plane + (size_t)ppx[pk] * 8;
            float a = acc[pk];
#pragma unroll
            for (int dm = -1; dm <= 1; ++dm)
#pragma unroll
                for (int dn = -1; dn <= 1; ++dn) {
                    const int tap = (dm + 1) * 3 + (dn + 1);
                    int4 v = *(const int4*)(base + (dm * MP + dn) * 8);
                    float4 w0 = wa[tap], w1 = wb[tap];
                    a = fmaf(lo16f((unsigned)v.x), w0.x, a);
                    a = fmaf(hi16f((unsigned)v.x), w0.y, a);
                    a = fmaf(lo16f((unsigned)v.y), w0.z, a);
                    a = fmaf(hi16f((unsigned)v.y), w0.w, a);
                    a = fmaf(lo16f((unsigned)v.z), w1.x, a);
                    a = fmaf(hi16f((unsigned)v.z), w1.y, a);
                    a = fmaf(lo16f((unsigned)v.w), w1.z, a);
                    a = fmaf(hi16f((unsigned)v.w), w1.w, a);
                }
            acc[pk] = a;
        }
    }
#pragma unroll
    for (int pk = 0; pk < 2; ++pk)
        out[(size_t)img * 1024 + tid + pk * 512] = rcp_(1.f + exp2_(-SCALE * acc[pk]));
}

extern "C" void kernel_launch(void* const* d_in, const int* in_sizes, int n_in,
                              void* d_out, int out_size, void* d_ws, size_t ws_size,
                              hipStream_t stream) {
    const float* x   = (const float*)d_in[0];
    const float* Wih = (const float*)d_in[1];
    const float* Whh = (const float*)d_in[2];
    const float* bih = (const float*)d_in[3];
    const float* bhh = (const float*)d_in[4];
    const float* cw  = (const float*)d_in[5];
    const float* cb  = (const float*)d_in[6];
    float* out = (float*)d_out;
    unsigned short* sp = (unsigned short*)d_ws;  // bf16 (B,T, chunk4, 34,34, 8ch)

    zero_halo<<<792, 512, 0, stream>>>(sp);
    lstm_k10<<<512, 256, 0, stream>>>(x, Wih, Whh, bih, bhh, sp);
    conv_k4<<<Bn * Tn, 512, 0, stream>>>(sp, cw, cb, out);
}